// Round 14
// baseline (318.118 us; speedup 1.0000x reference)
//
#include <hip/hip_runtime.h>
#include <hip/hip_fp16.h>
#include <cstddef>
#include <cstdint>

#define NM  50000
#define HID 160
#define NEI 8
#define AST 168     // padded LDS row stride (ushorts)
#define HHROW 512   // hh row bytes: 320 B bf16 h | 160 B e5m2 hU(-log2e scaled) | 32 pad
#define NB64 782    // ceil(50000/64) 64-row tiles
#define FTILES 1564 // 32-row frag tiles covered by 782 64-row blocks

#define NEGL2E (-1.44269504f)

// packed-weight offsets (ushort units), bf16 hi-only
#define WPX   0        // [30nt][5ks][64l][8]: Wzx | Wr | Whx
#define WPU   76800    // Ur
#define WPZH  102400   // Wzh
#define WPHH  128000   // Whh

typedef __attribute__((ext_vector_type(8))) short  short8;
typedef __attribute__((ext_vector_type(4))) float  f32x4;
typedef __attribute__((ext_vector_type(2))) float  float2v;
typedef __attribute__((ext_vector_type(4))) ushort ushort4v;

__device__ __forceinline__ ushort f2bf(float f) {
    union { float f; uint32_t u; } v; v.f = f;
    const uint32_t r = v.u + 0x7fffu + ((v.u >> 16) & 1u);   // RNE
    return (ushort)(r >> 16);
}
__device__ __forceinline__ float bf2f(ushort h) {
    union { uint32_t u; float f; } v; v.u = ((uint32_t)h) << 16;
    return v.f;
}
// fp8 e5m2 == truncated f16 (OCP bf8)
__device__ __forceinline__ uint32_t f2e5(float v) {
    union { __half h; ushort u; } c; c.h = __float2half(v);
    const ushort r = c.u + 0x7F + ((c.u >> 8) & 1);
    return (uint32_t)(r >> 8) & 0xFF;
}
__device__ __forceinline__ float e5m2f(uint32_t byte) {
    union { ushort u; __half h; } c; c.u = (ushort)(byte << 8);
    return __half2float(c.h);
}

#if defined(__has_builtin)
#  if __has_builtin(__builtin_amdgcn_cvt_pk_f32_bf8)
#    define HAS_HW_BF8 1
#  else
#    define HAS_HW_BF8 0
#  endif
#  if __has_builtin(__builtin_amdgcn_exp2f)
#    define HEXP2(x) __builtin_amdgcn_exp2f(x)
#  else
#    define HEXP2(x) exp2f(x)
#  endif
#else
#  define HAS_HW_BF8 0
#  define HEXP2(x) exp2f(x)
#endif

__device__ __forceinline__ float rcpfa(float x) { return __builtin_amdgcn_rcpf(x); }

// decode 2 e5m2 bytes -> 2 f32; HW path is 1 VALU op
template<bool HI>
__device__ __forceinline__ float2v bf8pair(uint32_t w) {
#if HAS_HW_BF8
    return __builtin_amdgcn_cvt_pk_f32_bf8((int)w, HI);
#else
    const uint32_t sh = HI ? 16u : 0u;
    float2v r;
    r[0] = e5m2f((w >> sh) & 0xFFu);
    r[1] = e5m2f((w >> (sh + 8)) & 0xFFu);
    return r;
#endif
}

// fast gate math: v_exp + v_rcp (1 ulp class — fine inside sigmoid/tanh)
__device__ __forceinline__ float sigf(float v)     { return rcpfa(1.f + HEXP2(NEGL2E * v)); }
__device__ __forceinline__ float tanhfast(float v) { return 2.f * rcpfa(1.f + HEXP2(2.f * NEGL2E * v)) - 1.f; }

// A-frag-linear slot for element block (row n, cols [8*c8, 8*c8+8)), 32-row frag tiles
__device__ __forceinline__ size_t afrag_idx(int n, int c8) {
    const int tile = n >> 5, mrow = n & 31;
    const int wrow = mrow >> 4, q = c8 >> 2;
    const int lane = (mrow & 15) + ((c8 & 3) << 4);
    return (size_t)((tile * 2 + wrow) * 5 + q) * 64 + lane;
}

// ---------------- weight pre-pack into MFMA B-fragment-linear order (bf16 hi only)
__global__ __launch_bounds__(256) void pack_weights(
    const float* __restrict__ Wz, const float* __restrict__ Wr,
    const float* __restrict__ Ur, const float* __restrict__ Wh,
    ushort* __restrict__ dst)
{
    const float* src; int off, stride, ntb = 0; ushort* hi;
    switch (blockIdx.x) {
        case 0:  src = Wz; off = 0;   stride = 320; hi = dst + WPX;  ntb = 0;  break;
        case 1:  src = Wr; off = 0;   stride = 160; hi = dst + WPX;  ntb = 10; break;
        case 2:  src = Wh; off = 0;   stride = 320; hi = dst + WPX;  ntb = 20; break;
        case 3:  src = Ur; off = 0;   stride = 160; hi = dst + WPU;  break;
        case 4:  src = Wz; off = 160; stride = 320; hi = dst + WPZH; break;
        default: src = Wh; off = 160; stride = 320; hi = dst + WPHH; break;
    }
    const int t = threadIdx.x, l = t & 63;
    for (int tile = t >> 6; tile < 50; tile += 4) {
        const int ntl = tile / 5, ks = tile % 5;
        const int n = ntl * 16 + (l & 15);
        const int k = ks * 32 + (l >> 4) * 8;
        const float* s = &src[(size_t)n * stride + off + k];
        const size_t o = ((size_t)((ntb + ntl) * 5 + ks) * 64 + l) * 8;
        #pragma unroll
        for (int j = 0; j < 8; ++j) hi[o + j] = f2bf(s[j]);
    }
}

// ---------------- x projections: 64-row tiles, grid (NB64, 2), y = wcol.
// All 4 waves of a block share one wcol -> B-frag stream is L1-broadcast.
__global__ __launch_bounds__(256) void xproj_gemm(
    const float* __restrict__ x, const ushort* __restrict__ wpack,
    const float* __restrict__ Wz_b, const float* __restrict__ Wh_b,
    ushort* __restrict__ xr, ushort* __restrict__ xzf, ushort* __restrict__ xhf,
    int M)
{
    __shared__ ushort As[64 * AST];
    const int t = threadIdx.x, m0 = blockIdx.x * 64, wcol = blockIdx.y;

    for (int idx = t; idx < 64 * 40; idx += 256) {
        const int m = idx / 40, k4 = (idx % 40) * 4;
        float4 v = make_float4(0.f, 0.f, 0.f, 0.f);
        if (m0 + m < M) v = *reinterpret_cast<const float4*>(&x[(size_t)(m0 + m) * HID + k4]);
        ushort4 hv;
        hv.x = f2bf(v.x); hv.y = f2bf(v.y); hv.z = f2bf(v.z); hv.w = f2bf(v.w);
        *reinterpret_cast<ushort4*>(&As[m * AST + k4]) = hv;
    }
    __syncthreads();

    const int w = t >> 6, l = t & 63;      // w = row-subtile 0..3
    const int ar = w * 16 + (l & 15);
    const int kg = (l >> 4) << 3;

    f32x4 accz[5], accr[5], acch[5];
    #pragma unroll
    for (int nt = 0; nt < 5; ++nt) {
        accz[nt] = (f32x4){0.f, 0.f, 0.f, 0.f};
        accr[nt] = (f32x4){0.f, 0.f, 0.f, 0.f};
        acch[nt] = (f32x4){0.f, 0.f, 0.f, 0.f};
    }

    const short8* WZx = reinterpret_cast<const short8*>(wpack + WPX);
    const short8* WRx = reinterpret_cast<const short8*>(wpack + WPX + 25600);
    const short8* WHx = reinterpret_cast<const short8*>(wpack + WPX + 51200);

    #pragma unroll
    for (int ks = 0; ks < 5; ++ks) {
        const short8 a = *reinterpret_cast<const short8*>(&As[ar * AST + ks * 32 + kg]);
        #pragma unroll
        for (int nt = 0; nt < 5; ++nt) {
            const int bi = (((wcol * 5 + nt) * 5 + ks) << 6) + l;
            accz[nt] = __builtin_amdgcn_mfma_f32_16x16x32_bf16(a, WZx[bi], accz[nt], 0, 0, 0);
            accr[nt] = __builtin_amdgcn_mfma_f32_16x16x32_bf16(a, WRx[bi], accr[nt], 0, 0, 0);
            acch[nt] = __builtin_amdgcn_mfma_f32_16x16x32_bf16(a, WHx[bi], acch[nt], 0, 0, 0);
        }
    }

    const int tile32 = (m0 >> 5) + (w >> 1);
    const int wrow32 = w & 1;
    const int r0l = w * 16 + ((l >> 4) << 2);   // block-local row
    const int cb = l & 15;
    const size_t fragbase = ((size_t)tile32 * 2 + wrow32) * 2 + wcol;

    // xz / xh: frag-direct stores (+bias)
    #pragma unroll
    for (int nt = 0; nt < 5; ++nt) {
        const int col = (wcol * 5 + nt) * 16 + cb;
        const float bz = Wz_b[col], bh = Wh_b[col];
        ushort4v vz, vh;
        #pragma unroll
        for (int r = 0; r < 4; ++r) {
            vz[r] = f2bf(accz[nt][r] + bz);
            vh[r] = f2bf(acch[nt][r] + bh);
        }
        *reinterpret_cast<ushort4v*>(&xzf[((fragbase * 5 + nt) * 64 + l) * 4]) = vz;
        *reinterpret_cast<ushort4v*>(&xhf[((fragbase * 5 + nt) * 64 + l) * 4]) = vh;
    }

    // xr (this wcol's 80 columns): LDS repack, pre-scaled by -log2e
    __syncthreads();
    #pragma unroll
    for (int nt = 0; nt < 5; ++nt) {
        const int col = (wcol * 5 + nt) * 16 + cb;
        #pragma unroll
        for (int r = 0; r < 4; ++r)
            As[(r0l + r) * AST + col] = f2bf(NEGL2E * accr[nt][r]);
    }
    __syncthreads();
    for (int idx = t; idx < 64 * 10; idx += 256) {
        const int m = idx / 10, g8 = (idx % 10) * 8;
        if (m0 + m < M)
            *reinterpret_cast<short8*>(&xr[(size_t)(m0 + m) * HID + wcol * 80 + g8]) =
                *reinterpret_cast<const short8*>(&As[m * AST + wcol * 80 + g8]);
    }
}

// ---------------- hU0: 64-row tiles; each wave computes all 160 cols (B shared 4-way)
__global__ __launch_bounds__(256, 4) void hU0_gemm(
    const float* __restrict__ h0, const ushort* __restrict__ wpack,
    const float* __restrict__ Ur_b, uint8_t* __restrict__ hh, int M)
{
    __shared__ ushort As[64 * AST];
    __shared__ uint8_t HuB[64 * 160];
    const int t = threadIdx.x, m0 = blockIdx.x * 64;

    for (int idx = t; idx < 64 * 40; idx += 256) {
        const int m = idx / 40, k4 = (idx % 40) * 4;
        float4 v = make_float4(0.f, 0.f, 0.f, 0.f);
        if (m0 + m < M) v = *reinterpret_cast<const float4*>(&h0[(size_t)(m0 + m) * HID + k4]);
        ushort4 hv;
        hv.x = f2bf(v.x); hv.y = f2bf(v.y); hv.z = f2bf(v.z); hv.w = f2bf(v.w);
        *reinterpret_cast<ushort4*>(&As[m * AST + k4]) = hv;
    }
    __syncthreads();

    for (int idx = t; idx < 64 * 20; idx += 256) {
        const int m = idx / 20, g8 = (idx % 20) * 8;
        if (m0 + m < M)
            *reinterpret_cast<short8*>(hh + (size_t)(m0 + m) * HHROW + g8 * 2) =
                *reinterpret_cast<const short8*>(&As[m * AST + g8]);
    }

    const int w = t >> 6, l = t & 63;
    const int ar = w * 16 + (l & 15);
    const int kg = (l >> 4) << 3;

    f32x4 acc[10];
    #pragma unroll
    for (int nt = 0; nt < 10; ++nt) acc[nt] = (f32x4){0.f, 0.f, 0.f, 0.f};

    const short8* WH = reinterpret_cast<const short8*>(wpack + WPU);

    #pragma unroll
    for (int ks = 0; ks < 5; ++ks) {
        const short8 a = *reinterpret_cast<const short8*>(&As[ar * AST + ks * 32 + kg]);
        #pragma unroll
        for (int nt = 0; nt < 10; ++nt)
            acc[nt] = __builtin_amdgcn_mfma_f32_16x16x32_bf16(a, WH[(nt * 5 + ks) * 64 + l], acc[nt], 0, 0, 0);
    }

    const int r0l = w * 16 + ((l >> 4) << 2);
    const int cb = l & 15;
    #pragma unroll
    for (int nt = 0; nt < 10; ++nt) {
        const int col = nt * 16 + cb;
        const float b = Ur_b[col];
        #pragma unroll
        for (int r = 0; r < 4; ++r)
            HuB[(r0l + r) * 160 + col] = (uint8_t)f2e5(NEGL2E * (acc[nt][r] + b));
    }
    __syncthreads();
    for (int idx = t; idx < 64 * 10; idx += 256) {
        const int m = idx / 10, g16 = (idx % 10) * 16;
        if (m0 + m < M)
            *reinterpret_cast<uint4*>(hh + (size_t)(m0 + m) * HHROW + 320 + g16) =
                *reinterpret_cast<const uint4*>(&HuB[m * 160 + g16]);
    }
}

// ---------------- standalone gather -> frag-linear sumh/sgh (unchanged).
__global__ __launch_bounds__(320, 2) void gather_kernel(
    const uint8_t* __restrict__ hh,     // [N][512B]: bf16 h | e5m2 hU(-log2e)
    const ushort* __restrict__ xr,      // [N][160] bf16, -log2e-scaled
    const int*    __restrict__ graph,
    ushort* __restrict__ sumhf,         // frag-linear bf16
    ushort* __restrict__ sghf)          // frag-linear bf16
{
    const int t = threadIdx.x;
    const int n = blockIdx.x * 16 + t / 20;     // 3125*16 == 50000 exactly
    const int c8 = t % 20, g8 = c8 * 8;

    const int4 ga = *reinterpret_cast<const int4*>(&graph[(size_t)n * NEI]);
    const int4 gb = *reinterpret_cast<const int4*>(&graph[(size_t)n * NEI + 4]);
    const int gi[8] = {ga.x, ga.y, ga.z, ga.w, gb.x, gb.y, gb.z, gb.w};

    const short8 xr8 = *reinterpret_cast<const short8*>(&xr[(size_t)n * HID + g8]);

    short8 hv[NEI]; uint2 hu[NEI];
    #pragma unroll
    for (int k = 0; k < NEI; ++k) {
        const uint8_t* row = hh + ((size_t)gi[k] << 9);   // HHROW=512 -> shift
        hv[k] = *reinterpret_cast<const short8*>(row + g8 * 2);
        hu[k] = *reinterpret_cast<const uint2*>(row + 320 + g8);
    }

    float2v xr2[4];
    {
        const uint32_t* xw = reinterpret_cast<const uint32_t*>(&xr8);
        #pragma unroll
        for (int i = 0; i < 4; ++i) {
            union { uint32_t u; float f; } a, b;
            a.u = xw[i] << 16;
            b.u = xw[i] & 0xFFFF0000u;
            xr2[i] = (float2v){a.f, b.f};
        }
    }

    float2v s2[4], g2[4];
    #pragma unroll
    for (int i = 0; i < 4; ++i) { s2[i] = (float2v){0.f, 0.f}; g2[i] = (float2v){0.f, 0.f}; }

    #pragma unroll
    for (int k = 0; k < NEI; ++k) {
        const uint32_t* hw = reinterpret_cast<const uint32_t*>(&hv[k]);
        float2v hu2[4];
        hu2[0] = bf8pair<false>(hu[k].x);
        hu2[1] = bf8pair<true >(hu[k].x);
        hu2[2] = bf8pair<false>(hu[k].y);
        hu2[3] = bf8pair<true >(hu[k].y);
        #pragma unroll
        for (int i = 0; i < 4; ++i) {
            union { uint32_t u; float f; } c0, c1;
            c0.u = hw[i] << 16;
            c1.u = hw[i] & 0xFFFF0000u;
            const float2v c = (float2v){c0.f, c1.f};
            const float2v tt = xr2[i] + hu2[i];                 // v_pk_add
            const float2v d  = (float2v){HEXP2(tt[0]), HEXP2(tt[1])} + (float2v){1.f, 1.f};
            const float2v r  = (float2v){rcpfa(d[0]), rcpfa(d[1])};
            s2[i] += c;                                         // v_pk_add
            g2[i] += r * c;                                     // v_pk_fma
        }
    }

    short8 sv, gv;
    #pragma unroll
    for (int i = 0; i < 4; ++i) {
        sv[2 * i]     = (short)f2bf(s2[i][0]);
        sv[2 * i + 1] = (short)f2bf(s2[i][1]);
        gv[2 * i]     = (short)f2bf(g2[i][0]);
        gv[2 * i + 1] = (short)f2bf(g2[i][1]);
    }
    const size_t fi = afrag_idx(n, c8);
    reinterpret_cast<short8*>(sumhf)[fi] = sv;
    reinterpret_cast<short8*>(sghf)[fi] = gv;
}

// ---------------- zh-GEMM + update (+ next-iter Ur tail), 64-row / 512-thread blocks.
// 8 waves = 4 row-subtiles x 2 wcol; B-frag streams shared 4-way via L1.
__global__ __launch_bounds__(512, 3) void gemm_zh(
    const ushort* __restrict__ sumhf, const ushort* __restrict__ sghf,
    const ushort* __restrict__ xzf, const ushort* __restrict__ xhf,
    const ushort* __restrict__ wpack, const float* __restrict__ Ur_b,
    float*   __restrict__ out,          // written only if write_out
    uint8_t* __restrict__ hh_next,      // written only if do_next
    int write_out, int do_next, int M)
{
    __shared__ ushort Az[64 * AST];     // tail only: h_out repack, then e5m2 bytes
    const int t = threadIdx.x, tile64 = blockIdx.x, m0 = tile64 * 64;
    const int w = t >> 6, l = t & 63;
    const int wcol = w >> 2, wsub = w & 3;
    const int tile32 = tile64 * 2 + (wsub >> 1);
    const int wrow32 = wsub & 1;

    // ---- issue ALL global reads up front (no barrier before MFMA) ----
    const size_t abase = ((size_t)tile32 * 2 + wrow32) * 5 * 64 + l;
    const short8* SA = reinterpret_cast<const short8*>(sumhf);
    const short8* SG = reinterpret_cast<const short8*>(sghf);
    short8 az[5], ag[5];
    #pragma unroll
    for (int ks = 0; ks < 5; ++ks) {
        az[ks] = SA[abase + (size_t)ks * 64];
        ag[ks] = SG[abase + (size_t)ks * 64];
    }
    const size_t fragbase = ((size_t)tile32 * 2 + wrow32) * 2 + wcol;
    ushort4v xz4[5], xh4[5];
    #pragma unroll
    for (int nt = 0; nt < 5; ++nt) {
        xz4[nt] = *reinterpret_cast<const ushort4v*>(&xzf[((fragbase * 5 + nt) * 64 + l) * 4]);
        xh4[nt] = *reinterpret_cast<const ushort4v*>(&xhf[((fragbase * 5 + nt) * 64 + l) * 4]);
    }

    // ---- identity B-frags for A->C transpose (one-hot bf16 1.0) ----
    const int hot0 = ((l >> 4) == ((l >> 3) & 1))     ? (l & 7) : -1;
    const int hot1 = ((l >> 4) == 2 + ((l >> 3) & 1)) ? (l & 7) : -1;
    short8 IF0, IF1;
    #pragma unroll
    for (int j = 0; j < 8; ++j) {
        IF0[j] = (short)((j == hot0) ? 0x3F80 : 0);
        IF1[j] = (short)((j == hot1) ? 0x3F80 : 0);
    }

    f32x4 accz[5], acch[5], accs[5];
    #pragma unroll
    for (int nt = 0; nt < 5; ++nt) {
        accz[nt] = (f32x4){0.f, 0.f, 0.f, 0.f};
        acch[nt] = (f32x4){0.f, 0.f, 0.f, 0.f};
        accs[nt] = (f32x4){0.f, 0.f, 0.f, 0.f};
    }

    {
        const short8* ZH = reinterpret_cast<const short8*>(wpack + WPZH);
        const short8* HHm = reinterpret_cast<const short8*>(wpack + WPHH);
        #pragma unroll
        for (int ks = 0; ks < 5; ++ks) {
            #pragma unroll
            for (int nt = 0; nt < 5; ++nt) {
                const int bi = (((wcol * 5 + nt) * 5 + ks) << 6) + l;
                accz[nt] = __builtin_amdgcn_mfma_f32_16x16x32_bf16(az[ks], ZH[bi], accz[nt], 0, 0, 0);
                acch[nt] = __builtin_amdgcn_mfma_f32_16x16x32_bf16(ag[ks], HHm[bi], acch[nt], 0, 0, 0);
            }
        }
        // sum_h -> C layout via identity (ct = wcol*5+nt; q=ct>>1, p=ct&1)
        if (wcol == 0) {
            accs[0] = __builtin_amdgcn_mfma_f32_16x16x32_bf16(az[0], IF0, accs[0], 0, 0, 0);
            accs[1] = __builtin_amdgcn_mfma_f32_16x16x32_bf16(az[0], IF1, accs[1], 0, 0, 0);
            accs[2] = __builtin_amdgcn_mfma_f32_16x16x32_bf16(az[1], IF0, accs[2], 0, 0, 0);
            accs[3] = __builtin_amdgcn_mfma_f32_16x16x32_bf16(az[1], IF1, accs[3], 0, 0, 0);
            accs[4] = __builtin_amdgcn_mfma_f32_16x16x32_bf16(az[2], IF0, accs[4], 0, 0, 0);
        } else {
            accs[0] = __builtin_amdgcn_mfma_f32_16x16x32_bf16(az[2], IF1, accs[0], 0, 0, 0);
            accs[1] = __builtin_amdgcn_mfma_f32_16x16x32_bf16(az[3], IF0, accs[1], 0, 0, 0);
            accs[2] = __builtin_amdgcn_mfma_f32_16x16x32_bf16(az[3], IF1, accs[2], 0, 0, 0);
            accs[3] = __builtin_amdgcn_mfma_f32_16x16x32_bf16(az[4], IF0, accs[3], 0, 0, 0);
            accs[4] = __builtin_amdgcn_mfma_f32_16x16x32_bf16(az[4], IF1, accs[4], 0, 0, 0);
        }
    }

    // ---- epilogue: v = (1-z)*sum_h + z*tanh(.) ----
    const int r0l = wsub * 16 + ((l >> 4) << 2);   // block-local row
    const int cb = l & 15;
    #pragma unroll
    for (int nt = 0; nt < 5; ++nt) {
        const int col = (wcol * 5 + nt) * 16 + cb;
        #pragma unroll
        for (int r = 0; r < 4; ++r) {
            const int m = m0 + r0l + r;
            float v = 0.f;
            if (m < M) {
                const float z = sigf(accz[nt][r] + bf2f(xz4[nt][r]));
                const float p = tanhfast(acch[nt][r] + bf2f(xh4[nt][r]));
                v = (1.f - z) * accs[nt][r] + z * p;
                if (m == 0) v = 0.f;
                if (write_out) out[(size_t)m * HID + col] = v;
            }
            accz[nt][r] = v;
        }
    }

    if (!do_next) return;

    // ---- tail: h_out -> row-major store + Ur-GEMM + e5m2 store ----
    #pragma unroll
    for (int nt = 0; nt < 5; ++nt) {
        const int col = (wcol * 5 + nt) * 16 + cb;
        #pragma unroll
        for (int r = 0; r < 4; ++r)
            Az[(r0l + r) * AST + col] = f2bf(accz[nt][r]);
    }
    __syncthreads();

    for (int idx = t; idx < 64 * 20; idx += 512) {
        const int m = idx / 20, g8 = (idx % 20) * 8;
        if (m0 + m < M)
            *reinterpret_cast<short8*>(hh_next + (size_t)(m0 + m) * HHROW + g8 * 2) =
                *reinterpret_cast<const short8*>(&Az[m * AST + g8]);
    }

    const int ar = wsub * 16 + (l & 15);
    const int kg = (l >> 4) << 3;
    #pragma unroll
    for (int nt = 0; nt < 5; ++nt) acch[nt] = (f32x4){0.f, 0.f, 0.f, 0.f};
    {
        const short8* WH = reinterpret_cast<const short8*>(wpack + WPU);
        #pragma unroll
        for (int ks = 0; ks < 5; ++ks) {
            const short8 a = *reinterpret_cast<const short8*>(&Az[ar * AST + ks * 32 + kg]);
            #pragma unroll
            for (int nt = 0; nt < 5; ++nt)
                acch[nt] = __builtin_amdgcn_mfma_f32_16x16x32_bf16(a, WH[(((wcol * 5 + nt) * 5 + ks) << 6) + l], acch[nt], 0, 0, 0);
        }
    }
    __syncthreads();   // all Az reads done; overlay byte buffer
    uint8_t* Agb = reinterpret_cast<uint8_t*>(Az);
    #pragma unroll
    for (int nt = 0; nt < 5; ++nt) {
        const int col = (wcol * 5 + nt) * 16 + cb;
        const float b = Ur_b[col];
        #pragma unroll
        for (int r = 0; r < 4; ++r)
            Agb[(r0l + r) * 160 + col] = (uint8_t)f2e5(NEGL2E * (acch[nt][r] + b));
    }
    __syncthreads();
    for (int idx = t; idx < 64 * 10; idx += 512) {
        const int m = idx / 10, g16 = (idx % 10) * 16;
        if (m0 + m < M)
            *reinterpret_cast<uint4*>(hh_next + (size_t)(m0 + m) * HHROW + 320 + g16) =
                *reinterpret_cast<const uint4*>(&Agb[m * 160 + g16]);
    }
}

extern "C" void kernel_launch(void* const* d_in, const int* in_sizes, int n_in,
                              void* d_out, int out_size, void* d_ws, size_t ws_size,
                              hipStream_t stream)
{
    const float* h0   = (const float*)d_in[0];
    const float* x    = (const float*)d_in[1];
    const int*   grf  = (const int*)  d_in[2];
    const float* Wz_w = (const float*)d_in[3];
    const float* Wz_b = (const float*)d_in[4];
    const float* Wr_w = (const float*)d_in[5];
    const float* Ur_w = (const float*)d_in[6];
    const float* Ur_b = (const float*)d_in[7];
    const float* Wh_w = (const float*)d_in[8];
    const float* Wh_b = (const float*)d_in[9];
    float* out = (float*)d_out;

    const size_t per  = (size_t)NM * HID;        // 8,000,000
    const size_t fsz  = (size_t)FTILES * 5120;   // frag-linear array ushorts
    ushort*  xr    = (ushort*)d_ws;                        // 16 MB
    ushort*  xzf   = xr + per;                             // 16 MB
    ushort*  xhf   = xzf + fsz;                            // 16 MB
    uint8_t* hh_a  = (uint8_t*)(xhf + fsz);                // 25.6 MB
    uint8_t* hh_b  = hh_a + (size_t)NM * HHROW;            // 25.6 MB
    ushort*  sumhf = (ushort*)(hh_b + (size_t)NM * HHROW); // 16 MB
    ushort*  sghf  = sumhf + fsz;                          // 16 MB
    ushort*  wpack = sghf + fsz;                           // 0.3 MB

    const dim3 zb(NB64);                                   // 782 blocks
    const dim3 sb(NM / 16), st(320);                       // 3125 blocks

    pack_weights<<<6, 256, 0, stream>>>(Wz_w, Wr_w, Ur_w, Wh_w, wpack);
    xproj_gemm<<<dim3(NB64, 2), 256, 0, stream>>>(x, wpack, Wz_b, Wh_b, xr, xzf, xhf, NM);
    hU0_gemm<<<zb, 256, 0, stream>>>(h0, wpack, Ur_b, hh_a, NM);

    gather_kernel<<<sb, st, 0, stream>>>(hh_a, xr, grf, sumhf, sghf);
    gemm_zh<<<zb, 512, 0, stream>>>(sumhf, sghf, xzf, xhf, wpack, Ur_b, out, hh_b, 0, 1, NM);
    gather_kernel<<<sb, st, 0, stream>>>(hh_b, xr, grf, sumhf, sghf);
    gemm_zh<<<zb, 512, 0, stream>>>(sumhf, sghf, xzf, xhf, wpack, Ur_b, out, hh_a, 0, 1, NM);
    gather_kernel<<<sb, st, 0, stream>>>(hh_a, xr, grf, sumhf, sghf);
    gemm_zh<<<zb, 512, 0, stream>>>(sumhf, sghf, xzf, xhf, wpack, Ur_b, out, hh_b, 1, 0, NM);
}

// Round 15
// 271.092 us; speedup vs baseline: 1.1735x; 1.1735x over previous
//
#include <hip/hip_runtime.h>
#include <hip/hip_fp16.h>
#include <cstddef>
#include <cstdint>

#define NM  50000
#define HID 160
#define NEI 8
#define AST 168     // padded LDS row stride (ushorts)
#define HHROW 512   // hh row bytes: 320 B bf16 h | 160 B e5m2 hU(-log2e scaled) | 32 pad
#define NBLK 1563   // ceil(50000/32) 32-row tiles

#define NEGL2E (-1.44269504f)

// packed-weight offsets (ushort units), bf16 hi-only
#define WPX   0        // [30nt][5ks][64l][8]: Wzx | Wr | Whx
#define WPU   76800    // Ur
#define WPZH  102400   // Wzh
#define WPHH  128000   // Whh

typedef __attribute__((ext_vector_type(8))) short  short8;
typedef __attribute__((ext_vector_type(4))) float  f32x4;
typedef __attribute__((ext_vector_type(2))) float  float2v;
typedef __attribute__((ext_vector_type(4))) ushort ushort4v;

__device__ __forceinline__ ushort f2bf(float f) {
    union { float f; uint32_t u; } v; v.f = f;
    const uint32_t r = v.u + 0x7fffu + ((v.u >> 16) & 1u);   // RNE
    return (ushort)(r >> 16);
}
__device__ __forceinline__ float bf2f(ushort h) {
    union { uint32_t u; float f; } v; v.u = ((uint32_t)h) << 16;
    return v.f;
}
// fp8 e5m2 == truncated f16 (OCP bf8)
__device__ __forceinline__ uint32_t f2e5(float v) {
    union { __half h; ushort u; } c; c.h = __float2half(v);
    const ushort r = c.u + 0x7F + ((c.u >> 8) & 1);
    return (uint32_t)(r >> 8) & 0xFF;
}
__device__ __forceinline__ float e5m2f(uint32_t byte) {
    union { ushort u; __half h; } c; c.u = (ushort)(byte << 8);
    return __half2float(c.h);
}

#if defined(__has_builtin)
#  if __has_builtin(__builtin_amdgcn_cvt_pk_f32_bf8)
#    define HAS_HW_BF8 1
#  else
#    define HAS_HW_BF8 0
#  endif
#  if __has_builtin(__builtin_amdgcn_exp2f)
#    define HEXP2(x) __builtin_amdgcn_exp2f(x)
#  else
#    define HEXP2(x) exp2f(x)
#  endif
#else
#  define HAS_HW_BF8 0
#  define HEXP2(x) exp2f(x)
#endif

__device__ __forceinline__ float rcpfa(float x) { return __builtin_amdgcn_rcpf(x); }

// decode 2 e5m2 bytes -> 2 f32; HW path is 1 VALU op
template<bool HI>
__device__ __forceinline__ float2v bf8pair(uint32_t w) {
#if HAS_HW_BF8
    return __builtin_amdgcn_cvt_pk_f32_bf8((int)w, HI);
#else
    const uint32_t sh = HI ? 16u : 0u;
    float2v r;
    r[0] = e5m2f((w >> sh) & 0xFFu);
    r[1] = e5m2f((w >> (sh + 8)) & 0xFFu);
    return r;
#endif
}

// fast gate math: v_exp + v_rcp (1 ulp class — fine inside sigmoid/tanh)
__device__ __forceinline__ float sigf(float v)     { return rcpfa(1.f + HEXP2(NEGL2E * v)); }
__device__ __forceinline__ float tanhfast(float v) { return 2.f * rcpfa(1.f + HEXP2(2.f * NEGL2E * v)) - 1.f; }

// A-frag-linear slot for element block (row n, cols [8*c8, 8*c8+8)), 32-row tiles
__device__ __forceinline__ size_t afrag_idx(int n, int c8) {
    const int tile = n >> 5, mrow = n & 31;
    const int wrow = mrow >> 4, q = c8 >> 2;
    const int lane = (mrow & 15) + ((c8 & 3) << 4);
    return (size_t)((tile * 2 + wrow) * 5 + q) * 64 + lane;
}

// ---------------- weight pre-pack into MFMA B-fragment-linear order (bf16 hi only)
__global__ __launch_bounds__(256) void pack_weights(
    const float* __restrict__ Wz, const float* __restrict__ Wr,
    const float* __restrict__ Ur, const float* __restrict__ Wh,
    ushort* __restrict__ dst)
{
    const float* src; int off, stride, ntb = 0; ushort* hi;
    switch (blockIdx.x) {
        case 0:  src = Wz; off = 0;   stride = 320; hi = dst + WPX;  ntb = 0;  break;
        case 1:  src = Wr; off = 0;   stride = 160; hi = dst + WPX;  ntb = 10; break;
        case 2:  src = Wh; off = 0;   stride = 320; hi = dst + WPX;  ntb = 20; break;
        case 3:  src = Ur; off = 0;   stride = 160; hi = dst + WPU;  break;
        case 4:  src = Wz; off = 160; stride = 320; hi = dst + WPZH; break;
        default: src = Wh; off = 160; stride = 320; hi = dst + WPHH; break;
    }
    const int t = threadIdx.x, l = t & 63;
    for (int tile = t >> 6; tile < 50; tile += 4) {
        const int ntl = tile / 5, ks = tile % 5;
        const int n = ntl * 16 + (l & 15);
        const int k = ks * 32 + (l >> 4) * 8;
        const float* s = &src[(size_t)n * stride + off + k];
        const size_t o = ((size_t)((ntb + ntl) * 5 + ks) * 64 + l) * 8;
        #pragma unroll
        for (int j = 0; j < 8; ++j) hi[o + j] = f2bf(s[j]);
    }
}

// ---------------- fused prologue, grid (NBLK, 2):
// y==0: xproj (single pass, 15 acc frags) — round-13 body verbatim.
// y==1: hU0 — round-13 body verbatim. Overlaps hU0 with xproj latency bubbles.
__global__ __launch_bounds__(256, 6) void prologue_gemm(
    const float* __restrict__ x, const float* __restrict__ h0,
    const ushort* __restrict__ wpack,
    const float* __restrict__ Wz_b, const float* __restrict__ Wh_b,
    const float* __restrict__ Ur_b,
    ushort* __restrict__ xr, ushort* __restrict__ xzf, ushort* __restrict__ xhf,
    uint8_t* __restrict__ hh, int M)
{
    __shared__ ushort As[32 * AST];
    __shared__ uint8_t HuB[32 * 160];
    const int t = threadIdx.x, m0 = blockIdx.x * 32;
    const int w = t >> 6, l = t & 63;
    const int wrow = w & 1, wcol = w >> 1;
    const int ar = wrow * 16 + (l & 15);
    const int kg = (l >> 4) << 3;
    const int r0l = wrow * 16 + ((l >> 4) << 2);
    const int cb = l & 15;

    if (blockIdx.y == 0) {
        // ---------- xproj ----------
        for (int idx = t; idx < 32 * 40; idx += 256) {
            const int m = idx / 40, k4 = (idx % 40) * 4;
            float4 v = make_float4(0.f, 0.f, 0.f, 0.f);
            if (m0 + m < M) v = *reinterpret_cast<const float4*>(&x[(size_t)(m0 + m) * HID + k4]);
            ushort4 hv;
            hv.x = f2bf(v.x); hv.y = f2bf(v.y); hv.z = f2bf(v.z); hv.w = f2bf(v.w);
            *reinterpret_cast<ushort4*>(&As[m * AST + k4]) = hv;
        }
        __syncthreads();

        f32x4 accz[5], accr[5], acch[5];
        #pragma unroll
        for (int nt = 0; nt < 5; ++nt) {
            accz[nt] = (f32x4){0.f, 0.f, 0.f, 0.f};
            accr[nt] = (f32x4){0.f, 0.f, 0.f, 0.f};
            acch[nt] = (f32x4){0.f, 0.f, 0.f, 0.f};
        }

        const short8* WZx = reinterpret_cast<const short8*>(wpack + WPX);
        const short8* WRx = reinterpret_cast<const short8*>(wpack + WPX + 25600);
        const short8* WHx = reinterpret_cast<const short8*>(wpack + WPX + 51200);

        #pragma unroll
        for (int ks = 0; ks < 5; ++ks) {
            const short8 a = *reinterpret_cast<const short8*>(&As[ar * AST + ks * 32 + kg]);
            #pragma unroll
            for (int nt = 0; nt < 5; ++nt) {
                const int bi = (((wcol * 5 + nt) * 5 + ks) << 6) + l;
                accz[nt] = __builtin_amdgcn_mfma_f32_16x16x32_bf16(a, WZx[bi], accz[nt], 0, 0, 0);
                accr[nt] = __builtin_amdgcn_mfma_f32_16x16x32_bf16(a, WRx[bi], accr[nt], 0, 0, 0);
                acch[nt] = __builtin_amdgcn_mfma_f32_16x16x32_bf16(a, WHx[bi], acch[nt], 0, 0, 0);
            }
        }

        const size_t fragbase = ((size_t)blockIdx.x * 2 + wrow) * 2 + wcol;

        #pragma unroll
        for (int nt = 0; nt < 5; ++nt) {
            const int col = (wcol * 5 + nt) * 16 + cb;
            const float bz = Wz_b[col], bh = Wh_b[col];
            ushort4v vz, vh;
            #pragma unroll
            for (int r = 0; r < 4; ++r) {
                vz[r] = f2bf(accz[nt][r] + bz);
                vh[r] = f2bf(acch[nt][r] + bh);
            }
            *reinterpret_cast<ushort4v*>(&xzf[((fragbase * 5 + nt) * 64 + l) * 4]) = vz;
            *reinterpret_cast<ushort4v*>(&xhf[((fragbase * 5 + nt) * 64 + l) * 4]) = vh;
        }

        __syncthreads();
        #pragma unroll
        for (int nt = 0; nt < 5; ++nt) {
            const int col = (wcol * 5 + nt) * 16 + cb;
            #pragma unroll
            for (int r = 0; r < 4; ++r)
                As[(r0l + r) * AST + col] = f2bf(NEGL2E * accr[nt][r]);
        }
        __syncthreads();
        for (int idx = t; idx < 32 * 20; idx += 256) {
            const int m = idx / 20, g8 = (idx % 20) * 8;
            if (m0 + m < M)
                *reinterpret_cast<short8*>(&xr[(size_t)(m0 + m) * HID + g8]) =
                    *reinterpret_cast<const short8*>(&As[m * AST + g8]);
        }
    } else {
        // ---------- hU0 ----------
        for (int idx = t; idx < 32 * 40; idx += 256) {
            const int m = idx / 40, k4 = (idx % 40) * 4;
            float4 v = make_float4(0.f, 0.f, 0.f, 0.f);
            if (m0 + m < M) v = *reinterpret_cast<const float4*>(&h0[(size_t)(m0 + m) * HID + k4]);
            ushort4 hv;
            hv.x = f2bf(v.x); hv.y = f2bf(v.y); hv.z = f2bf(v.z); hv.w = f2bf(v.w);
            *reinterpret_cast<ushort4*>(&As[m * AST + k4]) = hv;
        }
        __syncthreads();

        for (int idx = t; idx < 32 * 20; idx += 256) {
            const int m = idx / 20, g8 = (idx % 20) * 8;
            if (m0 + m < M)
                *reinterpret_cast<short8*>(hh + (size_t)(m0 + m) * HHROW + g8 * 2) =
                    *reinterpret_cast<const short8*>(&As[m * AST + g8]);
        }

        f32x4 acc[5];
        #pragma unroll
        for (int nt = 0; nt < 5; ++nt) acc[nt] = (f32x4){0.f, 0.f, 0.f, 0.f};

        const short8* WH = reinterpret_cast<const short8*>(wpack + WPU);

        #pragma unroll
        for (int ks = 0; ks < 5; ++ks) {
            const short8 a = *reinterpret_cast<const short8*>(&As[ar * AST + ks * 32 + kg]);
            #pragma unroll
            for (int nt = 0; nt < 5; ++nt)
                acc[nt] = __builtin_amdgcn_mfma_f32_16x16x32_bf16(a, WH[(((wcol * 5 + nt) * 5 + ks) << 6) + l], acc[nt], 0, 0, 0);
        }

        #pragma unroll
        for (int nt = 0; nt < 5; ++nt) {
            const int col = (wcol * 5 + nt) * 16 + cb;
            const float b = Ur_b[col];
            #pragma unroll
            for (int r = 0; r < 4; ++r)
                HuB[(r0l + r) * 160 + col] = (uint8_t)f2e5(NEGL2E * (acc[nt][r] + b));
        }
        __syncthreads();
        for (int idx = t; idx < 32 * 10; idx += 256) {
            const int m = idx / 10, g16 = (idx % 10) * 16;
            if (m0 + m < M)
                *reinterpret_cast<uint4*>(hh + (size_t)(m0 + m) * HHROW + 320 + g16) =
                    *reinterpret_cast<const uint4*>(&HuB[m * 160 + g16]);
        }
    }
}

// ---------------- standalone gather -> frag-linear sumh/sgh.
__global__ __launch_bounds__(320, 2) void gather_kernel(
    const uint8_t* __restrict__ hh,     // [N][512B]: bf16 h | e5m2 hU(-log2e)
    const ushort* __restrict__ xr,      // [N][160] bf16, -log2e-scaled
    const int*    __restrict__ graph,
    ushort* __restrict__ sumhf,         // frag-linear bf16
    ushort* __restrict__ sghf)          // frag-linear bf16
{
    const int t = threadIdx.x;
    const int n = blockIdx.x * 16 + t / 20;     // 3125*16 == 50000 exactly
    const int c8 = t % 20, g8 = c8 * 8;

    const int4 ga = *reinterpret_cast<const int4*>(&graph[(size_t)n * NEI]);
    const int4 gb = *reinterpret_cast<const int4*>(&graph[(size_t)n * NEI + 4]);
    const int gi[8] = {ga.x, ga.y, ga.z, ga.w, gb.x, gb.y, gb.z, gb.w};

    const short8 xr8 = *reinterpret_cast<const short8*>(&xr[(size_t)n * HID + g8]);

    short8 hv[NEI]; uint2 hu[NEI];
    #pragma unroll
    for (int k = 0; k < NEI; ++k) {
        const uint8_t* row = hh + ((size_t)gi[k] << 9);   // HHROW=512 -> shift
        hv[k] = *reinterpret_cast<const short8*>(row + g8 * 2);
        hu[k] = *reinterpret_cast<const uint2*>(row + 320 + g8);
    }

    float2v xr2[4];
    {
        const uint32_t* xw = reinterpret_cast<const uint32_t*>(&xr8);
        #pragma unroll
        for (int i = 0; i < 4; ++i) {
            union { uint32_t u; float f; } a, b;
            a.u = xw[i] << 16;
            b.u = xw[i] & 0xFFFF0000u;
            xr2[i] = (float2v){a.f, b.f};
        }
    }

    float2v s2[4], g2[4];
    #pragma unroll
    for (int i = 0; i < 4; ++i) { s2[i] = (float2v){0.f, 0.f}; g2[i] = (float2v){0.f, 0.f}; }

    #pragma unroll
    for (int k = 0; k < NEI; ++k) {
        const uint32_t* hw = reinterpret_cast<const uint32_t*>(&hv[k]);
        float2v hu2[4];
        hu2[0] = bf8pair<false>(hu[k].x);
        hu2[1] = bf8pair<true >(hu[k].x);
        hu2[2] = bf8pair<false>(hu[k].y);
        hu2[3] = bf8pair<true >(hu[k].y);
        #pragma unroll
        for (int i = 0; i < 4; ++i) {
            union { uint32_t u; float f; } c0, c1;
            c0.u = hw[i] << 16;
            c1.u = hw[i] & 0xFFFF0000u;
            const float2v c = (float2v){c0.f, c1.f};
            const float2v tt = xr2[i] + hu2[i];                 // v_pk_add
            const float2v d  = (float2v){HEXP2(tt[0]), HEXP2(tt[1])} + (float2v){1.f, 1.f};
            const float2v r  = (float2v){rcpfa(d[0]), rcpfa(d[1])};
            s2[i] += c;                                         // v_pk_add
            g2[i] += r * c;                                     // v_pk_fma
        }
    }

    short8 sv, gv;
    #pragma unroll
    for (int i = 0; i < 4; ++i) {
        sv[2 * i]     = (short)f2bf(s2[i][0]);
        sv[2 * i + 1] = (short)f2bf(s2[i][1]);
        gv[2 * i]     = (short)f2bf(g2[i][0]);
        gv[2 * i + 1] = (short)f2bf(g2[i][1]);
    }
    const size_t fi = afrag_idx(n, c8);
    reinterpret_cast<short8*>(sumhf)[fi] = sv;
    reinterpret_cast<short8*>(sghf)[fi] = gv;
}

// ---------------- zh-GEMM + update (+ next-iter Ur tail), frag-direct A operands.
__global__ __launch_bounds__(256, 3) void gemm_zh(
    const ushort* __restrict__ sumhf, const ushort* __restrict__ sghf,
    const ushort* __restrict__ xzf, const ushort* __restrict__ xhf,
    const ushort* __restrict__ wpack, const float* __restrict__ Ur_b,
    float*   __restrict__ out,          // written only if write_out
    uint8_t* __restrict__ hh_next,      // written only if do_next
    int write_out, int do_next, int M)
{
    __shared__ ushort Az[32 * AST];     // tail only: h_out repack, then e5m2 bytes
    const int t = threadIdx.x, tile = blockIdx.x, m0 = tile * 32;
    const int w = t >> 6, l = t & 63;
    const int wrow = w & 1, wcol = w >> 1;

    // ---- issue ALL global reads up front (no barrier before MFMA) ----
    const size_t abase = (size_t)(tile * 2 + wrow) * 5 * 64 + l;
    const short8* SA = reinterpret_cast<const short8*>(sumhf);
    const short8* SG = reinterpret_cast<const short8*>(sghf);
    short8 az[5], ag[5];
    #pragma unroll
    for (int ks = 0; ks < 5; ++ks) {
        az[ks] = SA[abase + (size_t)ks * 64];
        ag[ks] = SG[abase + (size_t)ks * 64];
    }
    const size_t fragbase = ((size_t)tile * 2 + wrow) * 2 + wcol;
    ushort4v xz4[5], xh4[5];
    #pragma unroll
    for (int nt = 0; nt < 5; ++nt) {
        xz4[nt] = *reinterpret_cast<const ushort4v*>(&xzf[((fragbase * 5 + nt) * 64 + l) * 4]);
        xh4[nt] = *reinterpret_cast<const ushort4v*>(&xhf[((fragbase * 5 + nt) * 64 + l) * 4]);
    }

    // ---- identity B-frags for A->C transpose (one-hot bf16 1.0) ----
    const int hot0 = ((l >> 4) == ((l >> 3) & 1))     ? (l & 7) : -1;
    const int hot1 = ((l >> 4) == 2 + ((l >> 3) & 1)) ? (l & 7) : -1;
    short8 IF0, IF1;
    #pragma unroll
    for (int j = 0; j < 8; ++j) {
        IF0[j] = (short)((j == hot0) ? 0x3F80 : 0);
        IF1[j] = (short)((j == hot1) ? 0x3F80 : 0);
    }

    f32x4 accz[5], acch[5], accs[5];
    #pragma unroll
    for (int nt = 0; nt < 5; ++nt) {
        accz[nt] = (f32x4){0.f, 0.f, 0.f, 0.f};
        acch[nt] = (f32x4){0.f, 0.f, 0.f, 0.f};
        accs[nt] = (f32x4){0.f, 0.f, 0.f, 0.f};
    }

    {
        const short8* ZH = reinterpret_cast<const short8*>(wpack + WPZH);
        const short8* HHm = reinterpret_cast<const short8*>(wpack + WPHH);
        #pragma unroll
        for (int ks = 0; ks < 5; ++ks) {
            #pragma unroll
            for (int nt = 0; nt < 5; ++nt) {
                const int bi = (((wcol * 5 + nt) * 5 + ks) << 6) + l;
                accz[nt] = __builtin_amdgcn_mfma_f32_16x16x32_bf16(az[ks], ZH[bi], accz[nt], 0, 0, 0);
                acch[nt] = __builtin_amdgcn_mfma_f32_16x16x32_bf16(ag[ks], HHm[bi], acch[nt], 0, 0, 0);
            }
        }
        // sum_h -> C layout via identity (ct = wcol*5+nt; q=ct>>1, p=ct&1)
        if (wcol == 0) {
            accs[0] = __builtin_amdgcn_mfma_f32_16x16x32_bf16(az[0], IF0, accs[0], 0, 0, 0);
            accs[1] = __builtin_amdgcn_mfma_f32_16x16x32_bf16(az[0], IF1, accs[1], 0, 0, 0);
            accs[2] = __builtin_amdgcn_mfma_f32_16x16x32_bf16(az[1], IF0, accs[2], 0, 0, 0);
            accs[3] = __builtin_amdgcn_mfma_f32_16x16x32_bf16(az[1], IF1, accs[3], 0, 0, 0);
            accs[4] = __builtin_amdgcn_mfma_f32_16x16x32_bf16(az[2], IF0, accs[4], 0, 0, 0);
        } else {
            accs[0] = __builtin_amdgcn_mfma_f32_16x16x32_bf16(az[2], IF1, accs[0], 0, 0, 0);
            accs[1] = __builtin_amdgcn_mfma_f32_16x16x32_bf16(az[3], IF0, accs[1], 0, 0, 0);
            accs[2] = __builtin_amdgcn_mfma_f32_16x16x32_bf16(az[3], IF1, accs[2], 0, 0, 0);
            accs[3] = __builtin_amdgcn_mfma_f32_16x16x32_bf16(az[4], IF0, accs[3], 0, 0, 0);
            accs[4] = __builtin_amdgcn_mfma_f32_16x16x32_bf16(az[4], IF1, accs[4], 0, 0, 0);
        }
    }

    // ---- epilogue: v = (1-z)*sum_h + z*tanh(.) ----
    const int r0l = wrow * 16 + ((l >> 4) << 2);
    const int cb = l & 15;
    #pragma unroll
    for (int nt = 0; nt < 5; ++nt) {
        const int col = (wcol * 5 + nt) * 16 + cb;
        #pragma unroll
        for (int r = 0; r < 4; ++r) {
            const int m = m0 + r0l + r;
            float v = 0.f;
            if (m < M) {
                const float z = sigf(accz[nt][r] + bf2f(xz4[nt][r]));
                const float p = tanhfast(acch[nt][r] + bf2f(xh4[nt][r]));
                v = (1.f - z) * accs[nt][r] + z * p;
                if (m == 0) v = 0.f;
                if (write_out) out[(size_t)m * HID + col] = v;
            }
            accz[nt][r] = v;
        }
    }

    if (!do_next) return;

    // ---- tail: h_out -> row-major store + Ur-GEMM + e5m2 store ----
    #pragma unroll
    for (int nt = 0; nt < 5; ++nt) {
        const int col = (wcol * 5 + nt) * 16 + cb;
        #pragma unroll
        for (int r = 0; r < 4; ++r)
            Az[(r0l + r) * AST + col] = f2bf(accz[nt][r]);
    }
    __syncthreads();

    for (int idx = t; idx < 32 * 20; idx += 256) {
        const int m = idx / 20, g8 = (idx % 20) * 8;
        if (m0 + m < M)
            *reinterpret_cast<short8*>(hh_next + (size_t)(m0 + m) * HHROW + g8 * 2) =
                *reinterpret_cast<const short8*>(&Az[m * AST + g8]);
    }

    const int ar = wrow * 16 + (l & 15);
    const int kg = (l >> 4) << 3;
    #pragma unroll
    for (int nt = 0; nt < 5; ++nt) acch[nt] = (f32x4){0.f, 0.f, 0.f, 0.f};
    {
        const short8* WH = reinterpret_cast<const short8*>(wpack + WPU);
        #pragma unroll
        for (int ks = 0; ks < 5; ++ks) {
            const short8 a = *reinterpret_cast<const short8*>(&Az[ar * AST + ks * 32 + kg]);
            #pragma unroll
            for (int nt = 0; nt < 5; ++nt)
                acch[nt] = __builtin_amdgcn_mfma_f32_16x16x32_bf16(a, WH[(((wcol * 5 + nt) * 5 + ks) << 6) + l], acch[nt], 0, 0, 0);
        }
    }
    __syncthreads();   // all Az reads done; overlay byte buffer
    uint8_t* Agb = reinterpret_cast<uint8_t*>(Az);
    #pragma unroll
    for (int nt = 0; nt < 5; ++nt) {
        const int col = (wcol * 5 + nt) * 16 + cb;
        const float b = Ur_b[col];
        #pragma unroll
        for (int r = 0; r < 4; ++r)
            Agb[(r0l + r) * 160 + col] = (uint8_t)f2e5(NEGL2E * (acch[nt][r] + b));
    }
    __syncthreads();
    for (int idx = t; idx < 32 * 10; idx += 256) {
        const int m = idx / 10, g16 = (idx % 10) * 16;
        if (m0 + m < M)
            *reinterpret_cast<uint4*>(hh_next + (size_t)(m0 + m) * HHROW + 320 + g16) =
                *reinterpret_cast<const uint4*>(&Agb[m * 160 + g16]);
    }
}

extern "C" void kernel_launch(void* const* d_in, const int* in_sizes, int n_in,
                              void* d_out, int out_size, void* d_ws, size_t ws_size,
                              hipStream_t stream)
{
    const float* h0   = (const float*)d_in[0];
    const float* x    = (const float*)d_in[1];
    const int*   grf  = (const int*)  d_in[2];
    const float* Wz_w = (const float*)d_in[3];
    const float* Wz_b = (const float*)d_in[4];
    const float* Wr_w = (const float*)d_in[5];
    const float* Ur_w = (const float*)d_in[6];
    const float* Ur_b = (const float*)d_in[7];
    const float* Wh_w = (const float*)d_in[8];
    const float* Wh_b = (const float*)d_in[9];
    float* out = (float*)d_out;

    const size_t per  = (size_t)NM * HID;        // 8,000,000
    const size_t fsz  = (size_t)NBLK * 5120;     // frag-linear array ushorts
    ushort*  xr    = (ushort*)d_ws;                        // 16 MB
    ushort*  xzf   = xr + per;                             // 16 MB
    ushort*  xhf   = xzf + fsz;                            // 16 MB
    uint8_t* hh_a  = (uint8_t*)(xhf + fsz);                // 25.6 MB
    uint8_t* hh_b  = hh_a + (size_t)NM * HHROW;            // 25.6 MB
    ushort*  sumhf = (ushort*)(hh_b + (size_t)NM * HHROW); // 16 MB
    ushort*  sghf  = sumhf + fsz;                          // 16 MB
    ushort*  wpack = sghf + fsz;                           // 0.3 MB

    const dim3 zb(NBLK), gt(256);                          // 1563 blocks
    const dim3 sb(NM / 16), st(320);                       // 3125 blocks

    pack_weights<<<6, 256, 0, stream>>>(Wz_w, Wr_w, Ur_w, Wh_w, wpack);
    prologue_gemm<<<dim3(NBLK, 2), gt, 0, stream>>>(x, h0, wpack, Wz_b, Wh_b, Ur_b,
                                                    xr, xzf, xhf, hh_a, NM);

    gather_kernel<<<sb, st, 0, stream>>>(hh_a, xr, grf, sumhf, sghf);
    gemm_zh<<<zb, gt, 0, stream>>>(sumhf, sghf, xzf, xhf, wpack, Ur_b, out, hh_b, 0, 1, NM);
    gather_kernel<<<sb, st, 0, stream>>>(hh_b, xr, grf, sumhf, sghf);
    gemm_zh<<<zb, gt, 0, stream>>>(sumhf, sghf, xzf, xhf, wpack, Ur_b, out, hh_a, 0, 1, NM);
    gather_kernel<<<sb, st, 0, stream>>>(hh_a, xr, grf, sumhf, sghf);
    gemm_zh<<<zb, gt, 0, stream>>>(sumhf, sghf, xzf, xhf, wpack, Ur_b, out, hh_b, 1, 0, NM);
}

// Round 16
// 251.260 us; speedup vs baseline: 1.2661x; 1.0789x over previous
//
#include <hip/hip_runtime.h>
#include <hip/hip_fp16.h>
#include <cstddef>
#include <cstdint>

#define NM  50000
#define HID 160
#define NEI 8
#define AST 168     // padded LDS row stride (ushorts)
#define HHROW 512   // hh row bytes: 320 B bf16 h | 160 B e5m2 hU(-log2e scaled) | 32 pad
#define NBLK 1563   // ceil(50000/32) 32-row tiles

#define NEGL2E (-1.44269504f)

// packed-weight offsets (ushort units), bf16 hi-only
#define WPX   0        // [30nt][5ks][64l][8]: Wzx | Wr | Whx
#define WPU   76800    // Ur
#define WPZH  102400   // Wzh
#define WPHH  128000   // Whh

typedef __attribute__((ext_vector_type(8))) short  short8;
typedef __attribute__((ext_vector_type(4))) float  f32x4;
typedef __attribute__((ext_vector_type(2))) float  float2v;
typedef __attribute__((ext_vector_type(4))) ushort ushort4v;

__device__ __forceinline__ ushort f2bf(float f) {
    union { float f; uint32_t u; } v; v.f = f;
    const uint32_t r = v.u + 0x7fffu + ((v.u >> 16) & 1u);   // RNE
    return (ushort)(r >> 16);
}
__device__ __forceinline__ float bf2f(ushort h) {
    union { uint32_t u; float f; } v; v.u = ((uint32_t)h) << 16;
    return v.f;
}
// fp8 e5m2 == truncated f16 (OCP bf8)
__device__ __forceinline__ uint32_t f2e5(float v) {
    union { __half h; ushort u; } c; c.h = __float2half(v);
    const ushort r = c.u + 0x7F + ((c.u >> 8) & 1);
    return (uint32_t)(r >> 8) & 0xFF;
}
__device__ __forceinline__ float e5m2f(uint32_t byte) {
    union { ushort u; __half h; } c; c.u = (ushort)(byte << 8);
    return __half2float(c.h);
}

#if defined(__has_builtin)
#  if __has_builtin(__builtin_amdgcn_cvt_pk_f32_bf8)
#    define HAS_HW_BF8 1
#  else
#    define HAS_HW_BF8 0
#  endif
#  if __has_builtin(__builtin_amdgcn_exp2f)
#    define HEXP2(x) __builtin_amdgcn_exp2f(x)
#  else
#    define HEXP2(x) exp2f(x)
#  endif
#else
#  define HAS_HW_BF8 0
#  define HEXP2(x) exp2f(x)
#endif

__device__ __forceinline__ float rcpfa(float x) { return __builtin_amdgcn_rcpf(x); }

// decode 2 e5m2 bytes -> 2 f32; HW path is 1 VALU op
template<bool HI>
__device__ __forceinline__ float2v bf8pair(uint32_t w) {
#if HAS_HW_BF8
    return __builtin_amdgcn_cvt_pk_f32_bf8((int)w, HI);
#else
    const uint32_t sh = HI ? 16u : 0u;
    float2v r;
    r[0] = e5m2f((w >> sh) & 0xFFu);
    r[1] = e5m2f((w >> (sh + 8)) & 0xFFu);
    return r;
#endif
}

// fast gate math: v_exp + v_rcp (1 ulp class — fine inside sigmoid/tanh)
__device__ __forceinline__ float sigf(float v)     { return rcpfa(1.f + HEXP2(NEGL2E * v)); }
__device__ __forceinline__ float tanhfast(float v) { return 2.f * rcpfa(1.f + HEXP2(2.f * NEGL2E * v)) - 1.f; }

// A-frag-linear slot for element block (row n, cols [8*c8, 8*c8+8)), 32-row tiles
__device__ __forceinline__ size_t afrag_idx(int n, int c8) {
    const int tile = n >> 5, mrow = n & 31;
    const int wrow = mrow >> 4, q = c8 >> 2;
    const int lane = (mrow & 15) + ((c8 & 3) << 4);
    return (size_t)((tile * 2 + wrow) * 5 + q) * 64 + lane;
}

// ---------------- weight pre-pack into MFMA B-fragment-linear order (bf16 hi only)
__global__ __launch_bounds__(256) void pack_weights(
    const float* __restrict__ Wz, const float* __restrict__ Wr,
    const float* __restrict__ Ur, const float* __restrict__ Wh,
    ushort* __restrict__ dst)
{
    const float* src; int off, stride, ntb = 0; ushort* hi;
    switch (blockIdx.x) {
        case 0:  src = Wz; off = 0;   stride = 320; hi = dst + WPX;  ntb = 0;  break;
        case 1:  src = Wr; off = 0;   stride = 160; hi = dst + WPX;  ntb = 10; break;
        case 2:  src = Wh; off = 0;   stride = 320; hi = dst + WPX;  ntb = 20; break;
        case 3:  src = Ur; off = 0;   stride = 160; hi = dst + WPU;  break;
        case 4:  src = Wz; off = 160; stride = 320; hi = dst + WPZH; break;
        default: src = Wh; off = 160; stride = 320; hi = dst + WPHH; break;
    }
    const int t = threadIdx.x, l = t & 63;
    for (int tile = t >> 6; tile < 50; tile += 4) {
        const int ntl = tile / 5, ks = tile % 5;
        const int n = ntl * 16 + (l & 15);
        const int k = ks * 32 + (l >> 4) * 8;
        const float* s = &src[(size_t)n * stride + off + k];
        const size_t o = ((size_t)((ntb + ntl) * 5 + ks) * 64 + l) * 8;
        #pragma unroll
        for (int j = 0; j < 8; ++j) hi[o + j] = f2bf(s[j]);
    }
}

// ---------------- x projections, SINGLE pass: reads x once, emits all three.
// xz/xh -> C-frag-linear (+bias); xr -> row-major, pre-scaled by -log2e.
__global__ __launch_bounds__(256) void xproj_gemm(
    const float* __restrict__ x, const ushort* __restrict__ wpack,
    const float* __restrict__ Wz_b, const float* __restrict__ Wh_b,
    ushort* __restrict__ xr, ushort* __restrict__ xzf, ushort* __restrict__ xhf,
    int M)
{
    __shared__ ushort As[32 * AST];
    const int t = threadIdx.x, m0 = blockIdx.x * 32;

    for (int idx = t; idx < 32 * 40; idx += 256) {
        const int m = idx / 40, k4 = (idx % 40) * 4;
        float4 v = make_float4(0.f, 0.f, 0.f, 0.f);
        if (m0 + m < M) v = *reinterpret_cast<const float4*>(&x[(size_t)(m0 + m) * HID + k4]);
        ushort4 hv;
        hv.x = f2bf(v.x); hv.y = f2bf(v.y); hv.z = f2bf(v.z); hv.w = f2bf(v.w);
        *reinterpret_cast<ushort4*>(&As[m * AST + k4]) = hv;
    }
    __syncthreads();

    const int w = t >> 6, l = t & 63;
    const int wrow = w & 1, wcol = w >> 1;
    const int ar = wrow * 16 + (l & 15);
    const int kg = (l >> 4) << 3;

    f32x4 accz[5], accr[5], acch[5];
    #pragma unroll
    for (int nt = 0; nt < 5; ++nt) {
        accz[nt] = (f32x4){0.f, 0.f, 0.f, 0.f};
        accr[nt] = (f32x4){0.f, 0.f, 0.f, 0.f};
        acch[nt] = (f32x4){0.f, 0.f, 0.f, 0.f};
    }

    const short8* WZx = reinterpret_cast<const short8*>(wpack + WPX);
    const short8* WRx = reinterpret_cast<const short8*>(wpack + WPX + 25600);
    const short8* WHx = reinterpret_cast<const short8*>(wpack + WPX + 51200);

    #pragma unroll
    for (int ks = 0; ks < 5; ++ks) {
        const short8 a = *reinterpret_cast<const short8*>(&As[ar * AST + ks * 32 + kg]);
        #pragma unroll
        for (int nt = 0; nt < 5; ++nt) {
            const int bi = (((wcol * 5 + nt) * 5 + ks) << 6) + l;
            accz[nt] = __builtin_amdgcn_mfma_f32_16x16x32_bf16(a, WZx[bi], accz[nt], 0, 0, 0);
            accr[nt] = __builtin_amdgcn_mfma_f32_16x16x32_bf16(a, WRx[bi], accr[nt], 0, 0, 0);
            acch[nt] = __builtin_amdgcn_mfma_f32_16x16x32_bf16(a, WHx[bi], acch[nt], 0, 0, 0);
        }
    }

    const int r0l = wrow * 16 + ((l >> 4) << 2);
    const int cb = l & 15;
    const size_t fragbase = ((size_t)blockIdx.x * 2 + wrow) * 2 + wcol;

    // xz / xh: frag-direct stores (+bias)
    #pragma unroll
    for (int nt = 0; nt < 5; ++nt) {
        const int col = (wcol * 5 + nt) * 16 + cb;
        const float bz = Wz_b[col], bh = Wh_b[col];
        ushort4v vz, vh;
        #pragma unroll
        for (int r = 0; r < 4; ++r) {
            vz[r] = f2bf(accz[nt][r] + bz);
            vh[r] = f2bf(acch[nt][r] + bh);
        }
        *reinterpret_cast<ushort4v*>(&xzf[((fragbase * 5 + nt) * 64 + l) * 4]) = vz;
        *reinterpret_cast<ushort4v*>(&xhf[((fragbase * 5 + nt) * 64 + l) * 4]) = vh;
    }

    // xr: row-major via LDS repack, pre-scaled
    __syncthreads();
    #pragma unroll
    for (int nt = 0; nt < 5; ++nt) {
        const int col = (wcol * 5 + nt) * 16 + cb;
        #pragma unroll
        for (int r = 0; r < 4; ++r)
            As[(r0l + r) * AST + col] = f2bf(NEGL2E * accr[nt][r]);
    }
    __syncthreads();
    for (int idx = t; idx < 32 * 20; idx += 256) {
        const int m = idx / 20, g8 = (idx % 20) * 8;
        if (m0 + m < M)
            *reinterpret_cast<short8*>(&xr[(size_t)(m0 + m) * HID + g8]) =
                *reinterpret_cast<const short8*>(&As[m * AST + g8]);
    }
}

// ---------------- hU0: hh[n] = [bf16(h0) | e5m2(-log2e*(h0 @ Ur^T + Ur_b))]
// 32-row tiles, 6 blocks/CU.
__global__ __launch_bounds__(256, 6) void hU0_gemm(
    const float* __restrict__ h0, const ushort* __restrict__ wpack,
    const float* __restrict__ Ur_b, uint8_t* __restrict__ hh, int M)
{
    __shared__ ushort As[32 * AST];
    __shared__ uint8_t HuB[32 * 160];
    const int t = threadIdx.x, m0 = blockIdx.x * 32;

    for (int idx = t; idx < 32 * 40; idx += 256) {
        const int m = idx / 40, k4 = (idx % 40) * 4;
        float4 v = make_float4(0.f, 0.f, 0.f, 0.f);
        if (m0 + m < M) v = *reinterpret_cast<const float4*>(&h0[(size_t)(m0 + m) * HID + k4]);
        ushort4 hv;
        hv.x = f2bf(v.x); hv.y = f2bf(v.y); hv.z = f2bf(v.z); hv.w = f2bf(v.w);
        *reinterpret_cast<ushort4*>(&As[m * AST + k4]) = hv;
    }
    __syncthreads();

    for (int idx = t; idx < 32 * 20; idx += 256) {
        const int m = idx / 20, g8 = (idx % 20) * 8;
        if (m0 + m < M)
            *reinterpret_cast<short8*>(hh + (size_t)(m0 + m) * HHROW + g8 * 2) =
                *reinterpret_cast<const short8*>(&As[m * AST + g8]);
    }

    const int w = t >> 6, l = t & 63;
    const int wrow = w & 1, wcol = w >> 1;
    const int ar = wrow * 16 + (l & 15);
    const int kg = (l >> 4) << 3;

    f32x4 acc[5];
    #pragma unroll
    for (int nt = 0; nt < 5; ++nt) acc[nt] = (f32x4){0.f, 0.f, 0.f, 0.f};

    const short8* WH = reinterpret_cast<const short8*>(wpack + WPU);

    #pragma unroll
    for (int ks = 0; ks < 5; ++ks) {
        const short8 a = *reinterpret_cast<const short8*>(&As[ar * AST + ks * 32 + kg]);
        #pragma unroll
        for (int nt = 0; nt < 5; ++nt)
            acc[nt] = __builtin_amdgcn_mfma_f32_16x16x32_bf16(a, WH[(((wcol * 5 + nt) * 5 + ks) << 6) + l], acc[nt], 0, 0, 0);
    }

    const int r0l = wrow * 16 + ((l >> 4) << 2);
    const int cb = l & 15;
    #pragma unroll
    for (int nt = 0; nt < 5; ++nt) {
        const int col = (wcol * 5 + nt) * 16 + cb;
        const float b = Ur_b[col];
        #pragma unroll
        for (int r = 0; r < 4; ++r)
            HuB[(r0l + r) * 160 + col] = (uint8_t)f2e5(NEGL2E * (acc[nt][r] + b));
    }
    __syncthreads();
    for (int idx = t; idx < 32 * 10; idx += 256) {
        const int m = idx / 10, g16 = (idx % 10) * 16;
        if (m0 + m < M)
            *reinterpret_cast<uint4*>(hh + (size_t)(m0 + m) * HHROW + 320 + g16) =
                *reinterpret_cast<const uint4*>(&HuB[m * 160 + g16]);
    }
}

// ---------------- standalone gather -> frag-linear sumh/sgh.
__global__ __launch_bounds__(320, 2) void gather_kernel(
    const uint8_t* __restrict__ hh,     // [N][512B]: bf16 h | e5m2 hU(-log2e)
    const ushort* __restrict__ xr,      // [N][160] bf16, -log2e-scaled
    const int*    __restrict__ graph,
    ushort* __restrict__ sumhf,         // frag-linear bf16
    ushort* __restrict__ sghf)          // frag-linear bf16
{
    const int t = threadIdx.x;
    const int n = blockIdx.x * 16 + t / 20;     // 3125*16 == 50000 exactly
    const int c8 = t % 20, g8 = c8 * 8;

    const int4 ga = *reinterpret_cast<const int4*>(&graph[(size_t)n * NEI]);
    const int4 gb = *reinterpret_cast<const int4*>(&graph[(size_t)n * NEI + 4]);
    const int gi[8] = {ga.x, ga.y, ga.z, ga.w, gb.x, gb.y, gb.z, gb.w};

    const short8 xr8 = *reinterpret_cast<const short8*>(&xr[(size_t)n * HID + g8]);

    short8 hv[NEI]; uint2 hu[NEI];
    #pragma unroll
    for (int k = 0; k < NEI; ++k) {
        const uint8_t* row = hh + ((size_t)gi[k] << 9);   // HHROW=512 -> shift
        hv[k] = *reinterpret_cast<const short8*>(row + g8 * 2);
        hu[k] = *reinterpret_cast<const uint2*>(row + 320 + g8);
    }

    float2v xr2[4];
    {
        const uint32_t* xw = reinterpret_cast<const uint32_t*>(&xr8);
        #pragma unroll
        for (int i = 0; i < 4; ++i) {
            union { uint32_t u; float f; } a, b;
            a.u = xw[i] << 16;
            b.u = xw[i] & 0xFFFF0000u;
            xr2[i] = (float2v){a.f, b.f};
        }
    }

    float2v s2[4], g2[4];
    #pragma unroll
    for (int i = 0; i < 4; ++i) { s2[i] = (float2v){0.f, 0.f}; g2[i] = (float2v){0.f, 0.f}; }

    #pragma unroll
    for (int k = 0; k < NEI; ++k) {
        const uint32_t* hw = reinterpret_cast<const uint32_t*>(&hv[k]);
        float2v hu2[4];
        hu2[0] = bf8pair<false>(hu[k].x);
        hu2[1] = bf8pair<true >(hu[k].x);
        hu2[2] = bf8pair<false>(hu[k].y);
        hu2[3] = bf8pair<true >(hu[k].y);
        #pragma unroll
        for (int i = 0; i < 4; ++i) {
            union { uint32_t u; float f; } c0, c1;
            c0.u = hw[i] << 16;
            c1.u = hw[i] & 0xFFFF0000u;
            const float2v c = (float2v){c0.f, c1.f};
            const float2v tt = xr2[i] + hu2[i];                 // v_pk_add
            const float2v d  = (float2v){HEXP2(tt[0]), HEXP2(tt[1])} + (float2v){1.f, 1.f};
            const float2v r  = (float2v){rcpfa(d[0]), rcpfa(d[1])};
            s2[i] += c;                                         // v_pk_add
            g2[i] += r * c;                                     // v_pk_fma
        }
    }

    short8 sv, gv;
    #pragma unroll
    for (int i = 0; i < 4; ++i) {
        sv[2 * i]     = (short)f2bf(s2[i][0]);
        sv[2 * i + 1] = (short)f2bf(s2[i][1]);
        gv[2 * i]     = (short)f2bf(g2[i][0]);
        gv[2 * i + 1] = (short)f2bf(g2[i][1]);
    }
    const size_t fi = afrag_idx(n, c8);
    reinterpret_cast<short8*>(sumhf)[fi] = sv;
    reinterpret_cast<short8*>(sghf)[fi] = gv;
}

// ---------------- zh-GEMM + update (+ next-iter Ur tail), frag-direct A operands.
__global__ __launch_bounds__(256, 3) void gemm_zh(
    const ushort* __restrict__ sumhf, const ushort* __restrict__ sghf,
    const ushort* __restrict__ xzf, const ushort* __restrict__ xhf,
    const ushort* __restrict__ wpack, const float* __restrict__ Ur_b,
    float*   __restrict__ out,          // written only if write_out
    uint8_t* __restrict__ hh_next,      // written only if do_next
    int write_out, int do_next, int M)
{
    __shared__ ushort Az[32 * AST];     // tail only: h_out repack, then e5m2 bytes
    const int t = threadIdx.x, tile = blockIdx.x, m0 = tile * 32;
    const int w = t >> 6, l = t & 63;
    const int wrow = w & 1, wcol = w >> 1;

    // ---- issue ALL global reads up front (no barrier before MFMA) ----
    const size_t abase = (size_t)(tile * 2 + wrow) * 5 * 64 + l;
    const short8* SA = reinterpret_cast<const short8*>(sumhf);
    const short8* SG = reinterpret_cast<const short8*>(sghf);
    short8 az[5], ag[5];
    #pragma unroll
    for (int ks = 0; ks < 5; ++ks) {
        az[ks] = SA[abase + (size_t)ks * 64];
        ag[ks] = SG[abase + (size_t)ks * 64];
    }
    const size_t fragbase = ((size_t)tile * 2 + wrow) * 2 + wcol;
    ushort4v xz4[5], xh4[5];
    #pragma unroll
    for (int nt = 0; nt < 5; ++nt) {
        xz4[nt] = *reinterpret_cast<const ushort4v*>(&xzf[((fragbase * 5 + nt) * 64 + l) * 4]);
        xh4[nt] = *reinterpret_cast<const ushort4v*>(&xhf[((fragbase * 5 + nt) * 64 + l) * 4]);
    }

    // ---- identity B-frags for A->C transpose (one-hot bf16 1.0) ----
    const int hot0 = ((l >> 4) == ((l >> 3) & 1))     ? (l & 7) : -1;
    const int hot1 = ((l >> 4) == 2 + ((l >> 3) & 1)) ? (l & 7) : -1;
    short8 IF0, IF1;
    #pragma unroll
    for (int j = 0; j < 8; ++j) {
        IF0[j] = (short)((j == hot0) ? 0x3F80 : 0);
        IF1[j] = (short)((j == hot1) ? 0x3F80 : 0);
    }

    f32x4 accz[5], acch[5], accs[5];
    #pragma unroll
    for (int nt = 0; nt < 5; ++nt) {
        accz[nt] = (f32x4){0.f, 0.f, 0.f, 0.f};
        acch[nt] = (f32x4){0.f, 0.f, 0.f, 0.f};
        accs[nt] = (f32x4){0.f, 0.f, 0.f, 0.f};
    }

    {
        const short8* ZH = reinterpret_cast<const short8*>(wpack + WPZH);
        const short8* HHm = reinterpret_cast<const short8*>(wpack + WPHH);
        #pragma unroll
        for (int ks = 0; ks < 5; ++ks) {
            #pragma unroll
            for (int nt = 0; nt < 5; ++nt) {
                const int bi = (((wcol * 5 + nt) * 5 + ks) << 6) + l;
                accz[nt] = __builtin_amdgcn_mfma_f32_16x16x32_bf16(az[ks], ZH[bi], accz[nt], 0, 0, 0);
                acch[nt] = __builtin_amdgcn_mfma_f32_16x16x32_bf16(ag[ks], HHm[bi], acch[nt], 0, 0, 0);
            }
        }
        // sum_h -> C layout via identity (ct = wcol*5+nt; q=ct>>1, p=ct&1)
        if (wcol == 0) {
            accs[0] = __builtin_amdgcn_mfma_f32_16x16x32_bf16(az[0], IF0, accs[0], 0, 0, 0);
            accs[1] = __builtin_amdgcn_mfma_f32_16x16x32_bf16(az[0], IF1, accs[1], 0, 0, 0);
            accs[2] = __builtin_amdgcn_mfma_f32_16x16x32_bf16(az[1], IF0, accs[2], 0, 0, 0);
            accs[3] = __builtin_amdgcn_mfma_f32_16x16x32_bf16(az[1], IF1, accs[3], 0, 0, 0);
            accs[4] = __builtin_amdgcn_mfma_f32_16x16x32_bf16(az[2], IF0, accs[4], 0, 0, 0);
        } else {
            accs[0] = __builtin_amdgcn_mfma_f32_16x16x32_bf16(az[2], IF1, accs[0], 0, 0, 0);
            accs[1] = __builtin_amdgcn_mfma_f32_16x16x32_bf16(az[3], IF0, accs[1], 0, 0, 0);
            accs[2] = __builtin_amdgcn_mfma_f32_16x16x32_bf16(az[3], IF1, accs[2], 0, 0, 0);
            accs[3] = __builtin_amdgcn_mfma_f32_16x16x32_bf16(az[4], IF0, accs[3], 0, 0, 0);
            accs[4] = __builtin_amdgcn_mfma_f32_16x16x32_bf16(az[4], IF1, accs[4], 0, 0, 0);
        }
    }

    // ---- epilogue: v = (1-z)*sum_h + z*tanh(.) ----
    const int r0l = wrow * 16 + ((l >> 4) << 2);
    const int cb = l & 15;
    #pragma unroll
    for (int nt = 0; nt < 5; ++nt) {
        const int col = (wcol * 5 + nt) * 16 + cb;
        #pragma unroll
        for (int r = 0; r < 4; ++r) {
            const int m = m0 + r0l + r;
            float v = 0.f;
            if (m < M) {
                const float z = sigf(accz[nt][r] + bf2f(xz4[nt][r]));
                const float p = tanhfast(acch[nt][r] + bf2f(xh4[nt][r]));
                v = (1.f - z) * accs[nt][r] + z * p;
                if (m == 0) v = 0.f;
                if (write_out) out[(size_t)m * HID + col] = v;
            }
            accz[nt][r] = v;
        }
    }

    if (!do_next) return;

    // ---- tail: h_out -> row-major store + Ur-GEMM + e5m2 store ----
    #pragma unroll
    for (int nt = 0; nt < 5; ++nt) {
        const int col = (wcol * 5 + nt) * 16 + cb;
        #pragma unroll
        for (int r = 0; r < 4; ++r)
            Az[(r0l + r) * AST + col] = f2bf(accz[nt][r]);
    }
    __syncthreads();

    for (int idx = t; idx < 32 * 20; idx += 256) {
        const int m = idx / 20, g8 = (idx % 20) * 8;
        if (m0 + m < M)
            *reinterpret_cast<short8*>(hh_next + (size_t)(m0 + m) * HHROW + g8 * 2) =
                *reinterpret_cast<const short8*>(&Az[m * AST + g8]);
    }

    const int ar = wrow * 16 + (l & 15);
    const int kg = (l >> 4) << 3;
    #pragma unroll
    for (int nt = 0; nt < 5; ++nt) acch[nt] = (f32x4){0.f, 0.f, 0.f, 0.f};
    {
        const short8* WH = reinterpret_cast<const short8*>(wpack + WPU);
        #pragma unroll
        for (int ks = 0; ks < 5; ++ks) {
            const short8 a = *reinterpret_cast<const short8*>(&Az[ar * AST + ks * 32 + kg]);
            #pragma unroll
            for (int nt = 0; nt < 5; ++nt)
                acch[nt] = __builtin_amdgcn_mfma_f32_16x16x32_bf16(a, WH[(((wcol * 5 + nt) * 5 + ks) << 6) + l], acch[nt], 0, 0, 0);
        }
    }
    __syncthreads();   // all Az reads done; overlay byte buffer
    uint8_t* Agb = reinterpret_cast<uint8_t*>(Az);
    #pragma unroll
    for (int nt = 0; nt < 5; ++nt) {
        const int col = (wcol * 5 + nt) * 16 + cb;
        const float b = Ur_b[col];
        #pragma unroll
        for (int r = 0; r < 4; ++r)
            Agb[(r0l + r) * 160 + col] = (uint8_t)f2e5(NEGL2E * (acch[nt][r] + b));
    }
    __syncthreads();
    for (int idx = t; idx < 32 * 10; idx += 256) {
        const int m = idx / 10, g16 = (idx % 10) * 16;
        if (m0 + m < M)
            *reinterpret_cast<uint4*>(hh_next + (size_t)(m0 + m) * HHROW + 320 + g16) =
                *reinterpret_cast<const uint4*>(&Agb[m * 160 + g16]);
    }
}

extern "C" void kernel_launch(void* const* d_in, const int* in_sizes, int n_in,
                              void* d_out, int out_size, void* d_ws, size_t ws_size,
                              hipStream_t stream)
{
    const float* h0   = (const float*)d_in[0];
    const float* x    = (const float*)d_in[1];
    const int*   grf  = (const int*)  d_in[2];
    const float* Wz_w = (const float*)d_in[3];
    const float* Wz_b = (const float*)d_in[4];
    const float* Wr_w = (const float*)d_in[5];
    const float* Ur_w = (const float*)d_in[6];
    const float* Ur_b = (const float*)d_in[7];
    const float* Wh_w = (const float*)d_in[8];
    const float* Wh_b = (const float*)d_in[9];
    float* out = (float*)d_out;

    const size_t per  = (size_t)NM * HID;        // 8,000,000
    const size_t fsz  = (size_t)NBLK * 5120;     // frag-linear array ushorts
    ushort*  xr    = (ushort*)d_ws;                        // 16 MB
    ushort*  xzf   = xr + per;                             // 16 MB
    ushort*  xhf   = xzf + fsz;                            // 16 MB
    uint8_t* hh_a  = (uint8_t*)(xhf + fsz);                // 25.6 MB
    uint8_t* hh_b  = hh_a + (size_t)NM * HHROW;            // 25.6 MB
    ushort*  sumhf = (ushort*)(hh_b + (size_t)NM * HHROW); // 16 MB
    ushort*  sghf  = sumhf + fsz;                          // 16 MB
    ushort*  wpack = sghf + fsz;                           // 0.3 MB

    const dim3 zb(NBLK), gt(256);                          // 1563 blocks
    const dim3 sb(NM / 16), st(320);                       // 3125 blocks

    pack_weights<<<6, 256, 0, stream>>>(Wz_w, Wr_w, Ur_w, Wh_w, wpack);
    xproj_gemm<<<zb, gt, 0, stream>>>(x, wpack, Wz_b, Wh_b, xr, xzf, xhf, NM);
    hU0_gemm<<<zb, gt, 0, stream>>>(h0, wpack, Ur_b, hh_a, NM);

    gather_kernel<<<sb, st, 0, stream>>>(hh_a, xr, grf, sumhf, sghf);
    gemm_zh<<<zb, gt, 0, stream>>>(sumhf, sghf, xzf, xhf, wpack, Ur_b, out, hh_b, 0, 1, NM);
    gather_kernel<<<sb, st, 0, stream>>>(hh_b, xr, grf, sumhf, sghf);
    gemm_zh<<<zb, gt, 0, stream>>>(sumhf, sghf, xzf, xhf, wpack, Ur_b, out, hh_a, 0, 1, NM);
    gather_kernel<<<sb, st, 0, stream>>>(hh_a, xr, grf, sumhf, sghf);
    gemm_zh<<<zb, gt, 0, stream>>>(sumhf, sghf, xzf, xhf, wpack, Ur_b, out, hh_b, 1, 0, NM);
}